// Round 1
// baseline (239.049 us; speedup 1.0000x reference)
//
#include <hip/hip_runtime.h>
#include <cstdint>
#include <cstddef>

// ---- problem constants ----
#define NBATCH   16384
#define NSEC     9
#define NOC      50        // conv output channels per section
#define NOCP     64        // padded to 4 MFMA n-tiles
#define KREAL    240       // 6*40 conv taps
#define KPAD     256       // padded K for 8 x 32 MFMA steps
#define XROW     1640      // 41*40 floats per batch
#define SECELEMS 360       // 9*40 floats per section slice
#define XS       392       // LDS row stride (elems): 49*8 -> odd multiple of 16B
#define OUTHALF  7372800   // 16384*50*9
#define THRESH   6.2f

typedef _Float16 half8  __attribute__((ext_vector_type(8)));
typedef _Float16 half4v __attribute__((ext_vector_type(4)));
typedef float    f32x4  __attribute__((ext_vector_type(4)));

// ---- k0: W fp32 [9][50][240] -> f16 [9][64][256], zero padded ----
__global__ __launch_bounds__(256)
void wconv_kernel(const float* __restrict__ W, _Float16* __restrict__ wks) {
    int idx = blockIdx.x * 256 + threadIdx.x;        // 0 .. 147455
    int k   = idx & 255;
    int ocp = (idx >> 8) & 63;
    int sec = idx >> 14;
    float v = 0.0f;
    if (ocp < NOC && k < KREAL)
        v = W[(size_t)(sec * NOC + ocp) * KREAL + k];
    wks[idx] = (_Float16)v;
}

// ---- k1: per block: one section x 64 batches. MFMA 16x16x32 f16. ----
// writes pots_tmp[sec][b][oc] (fp32, coalesced)
__global__ __launch_bounds__(256)
void conv_mfma_kernel(const float* __restrict__ x,
                      const _Float16* __restrict__ wks,
                      float* __restrict__ pots_tmp) {
    __shared__ _Float16 xs[64 * XS];

    const int tid  = threadIdx.x;
    const int tile = blockIdx.x;   // batch tile (64 batches)
    const int sec  = blockIdx.y;   // section

    // zero the K pad region [360, 392) for all 64 rows (A pad must be finite;
    // it multiplies W's zero pad k in [240,256))
    {
        half8 z = {};
        int b  = tid >> 2;
        int ko = SECELEMS + (tid & 3) * 8;
        *(half8*)&xs[b * XS + ko] = z;
    }

    // stage x slice: 64 batches x 360 floats -> f16 LDS (float4 loads, RNE cvt)
    const float* xg = x + (size_t)(tile * 64) * XROW + sec * 160; // sec*4 rows * 40
    for (int c = tid; c < 64 * 90; c += 256) {
        int b  = c / 90;
        int cc = c - b * 90;
        float4 v = *(const float4*)(xg + (size_t)b * XROW + cc * 4);
        half4v h;
        h.x = (_Float16)v.x; h.y = (_Float16)v.y;
        h.z = (_Float16)v.z; h.w = (_Float16)v.w;
        *(half4v*)&xs[b * XS + cc * 4] = h;
    }
    __syncthreads();

    const int lane = tid & 63;
    const int wave = tid >> 6;      // m-tile within block (16 batches each)
    const int l15  = lane & 15;
    const int quad = lane >> 4;

    f32x4 acc[4][4] = {};           // [h0][ntile]

    const _Float16* xrow = xs + (wave * 16 + l15) * XS;                 // A: m = l15
    const _Float16* wrow = wks + (size_t)sec * (NOCP * KPAD) + l15 * KPAD; // B: n = l15

    #pragma unroll
    for (int kk = 0; kk < 8; ++kk) {
        const int kb = kk * 32 + quad * 8;
        half8 av[4], bv[4];
        #pragma unroll
        for (int h = 0; h < 4; ++h)
            av[h] = *(const half8*)(xrow + h * 40 + kb);
        #pragma unroll
        for (int n = 0; n < 4; ++n)
            bv[n] = *(const half8*)(wrow + n * 16 * KPAD + kb);
        #pragma unroll
        for (int h = 0; h < 4; ++h)
            #pragma unroll
            for (int n = 0; n < 4; ++n)
                acc[h][n] = __builtin_amdgcn_mfma_f32_16x16x32_f16(
                                av[h], bv[n], acc[h][n], 0, 0, 0);
    }

    // epilogue: max over h0, store pots_tmp[sec][b][oc]
    // D layout: col(oc) = lane&15, row(batch) = quad*4 + r
    const int bbase = tile * 64 + wave * 16 + quad * 4;
    #pragma unroll
    for (int nt = 0; nt < 4; ++nt) {
        int oc = nt * 16 + l15;
        if (oc < NOC) {
            #pragma unroll
            for (int r = 0; r < 4; ++r) {
                float p = acc[0][nt][r];
                p = fmaxf(p, acc[1][nt][r]);
                p = fmaxf(p, acc[2][nt][r]);
                p = fmaxf(p, acc[3][nt][r]);
                pots_tmp[((size_t)sec * NBATCH + bbase + r) * NOC + oc] = p;
            }
        }
    }
}

// ---- k2: transpose [sec][b][oc] -> [b][oc][sec] + threshold ----
__global__ __launch_bounds__(256)
void transpose_kernel(const float* __restrict__ pots_tmp,
                      float* __restrict__ out) {
    __shared__ float t[32 * 450];
    const int tid = threadIdx.x;
    const int b0  = blockIdx.x * 32;

    for (int i = tid; i < NSEC * 32 * NOC; i += 256) {
        int sec = i / (32 * NOC);
        int r   = i - sec * (32 * NOC);
        int b   = r / NOC;
        int oc  = r - b * NOC;
        float v = pots_tmp[((size_t)sec * NBATCH + b0 + b) * NOC + oc];
        t[b * 450 + oc * NSEC + sec] = v;
    }
    __syncthreads();

    float* spk = out + OUTHALF;
    for (int i = tid; i < 32 * 450; i += 256) {
        float v = t[i];
        size_t g = (size_t)b0 * 450 + i;
        out[g] = v;
        spk[g] = (v > THRESH) ? 1.0f : 0.0f;
    }
}

// ---- fallback (only if ws too small): direct fp32, correct but slow ----
__global__ __launch_bounds__(256)
void naive_kernel(const float* __restrict__ x, const float* __restrict__ W,
                  float* __restrict__ out) {
    size_t idx = (size_t)blockIdx.x * 256 + threadIdx.x; // over 7372800
    if (idx >= OUTHALF) return;
    int s  = (int)(idx % NSEC);
    int oc = (int)((idx / NSEC) % NOC);
    int b  = (int)(idx / (NSEC * NOC));
    const float* xb = x + (size_t)b * XROW + s * 160;
    const float* w  = W + (size_t)(s * NOC + oc) * KREAL;
    float best = -1e30f;
    for (int h0 = 0; h0 < 4; ++h0) {
        float acc = 0.0f;
        for (int t = 0; t < KREAL; ++t)
            acc += xb[h0 * 40 + t] * w[t];
        best = fmaxf(best, acc);
    }
    out[idx] = best;
    out[OUTHALF + idx] = (best > THRESH) ? 1.0f : 0.0f;
}

extern "C" void kernel_launch(void* const* d_in, const int* in_sizes, int n_in,
                              void* d_out, int out_size, void* d_ws, size_t ws_size,
                              hipStream_t stream) {
    const float* x = (const float*)d_in[0];   // [16384,1,41,40]
    const float* W = (const float*)d_in[1];   // [9,50,1,6,40]
    float* out = (float*)d_out;               // pots(7372800) ++ spks(7372800)

    const size_t w_bytes   = (size_t)NSEC * NOCP * KPAD * sizeof(_Float16); // 294912
    const size_t pot_bytes = (size_t)NSEC * NBATCH * NOC * sizeof(float);   // 29491200

    if (ws_size < w_bytes + pot_bytes) {
        // safety fallback: no workspace dependency
        naive_kernel<<<(OUTHALF + 255) / 256, 256, 0, stream>>>(x, W, out);
        return;
    }

    _Float16* wks     = (_Float16*)d_ws;
    float*    potstmp = (float*)((char*)d_ws + w_bytes); // 256B-aligned offset

    wconv_kernel<<<(NSEC * NOCP * KPAD) / 256, 256, 0, stream>>>(W, wks);

    dim3 grid(NBATCH / 64, NSEC);
    conv_mfma_kernel<<<grid, 256, 0, stream>>>(x, wks, potstmp);

    transpose_kernel<<<NBATCH / 32, 256, 0, stream>>>(potstmp, out);
}

// Round 2
// 236.665 us; speedup vs baseline: 1.0101x; 1.0101x over previous
//
#include <hip/hip_runtime.h>
#include <cstdint>
#include <cstddef>

// ---- problem constants ----
#define NBATCH   16384
#define NSEC     9
#define NOC      50        // conv output channels per section
#define NOCP     64        // padded to 4 MFMA n-tiles
#define KREAL    240       // 6*40 conv taps
#define KPAD     256       // padded K for 8 x 32 MFMA steps
#define XROW     1640      // 41*40 floats per batch
#define XS2      1672      // LDS row stride (f16 elems): mult of 8 (16B align),
                           // lane dword-stride 836 % 32 = 4 -> balanced banks
#define TB       16        // batches per block
#define OUTHALF  7372800   // 16384*50*9
#define THRESH   6.2f

typedef _Float16 half8  __attribute__((ext_vector_type(8)));
typedef _Float16 half4v __attribute__((ext_vector_type(4)));
typedef float    f32x4  __attribute__((ext_vector_type(4)));

// ---- k0: W fp32 [9][50][240] -> f16 [9][64][256], zero padded ----
__global__ __launch_bounds__(256)
void wconv_kernel(const float* __restrict__ W, _Float16* __restrict__ wks) {
    int idx = blockIdx.x * 256 + threadIdx.x;        // 0 .. 147455
    int k   = idx & 255;
    int ocp = (idx >> 8) & 63;
    int sec = idx >> 14;
    float v = 0.0f;
    if (ocp < NOC && k < KREAL)
        v = W[(size_t)(sec * NOC + ocp) * KREAL + k];
    wks[idx] = (_Float16)v;
}

// ---- fused: 1 block = 16 batches x all 9 sections; x staged once;
//      output written in final [b][oc][sec] layout via LDS transpose ----
__global__ __launch_bounds__(256, 3)
void fused_kernel(const float* __restrict__ x,
                  const _Float16* __restrict__ wks,
                  float* __restrict__ out) {
    __shared__ __align__(16) _Float16 xs[TB * XS2];   // 53504 B; 3 blocks/CU

    const int tid = threadIdx.x;
    const size_t b0 = (size_t)blockIdx.x * TB;

    // zero K-pad region [1640,1656) of each row (A pad meets W's zero K-pad;
    // both zero => no NaN/Inf risk)
    if (tid < 32) {
        half8 z = {};
        int b = tid >> 1, off = XROW + (tid & 1) * 8;
        *(half8*)&xs[b * XS2 + off] = z;
    }

    // stage x[16][1640] fp32 -> f16 LDS (coalesced float4 loads)
    const float* xg = x + b0 * XROW;
    for (int c = tid; c < TB * 410; c += 256) {
        int b = c / 410, cc = c - b * 410;
        float4 v = *(const float4*)(xg + (size_t)b * XROW + cc * 4);
        half4v h;
        h.x = (_Float16)v.x; h.y = (_Float16)v.y;
        h.z = (_Float16)v.z; h.w = (_Float16)v.w;
        *(half4v*)&xs[b * XS2 + cc * 4] = h;
    }
    __syncthreads();

    const int lane = tid & 63;
    const int w    = tid >> 6;      // wave = oc tile (16 oc each)
    const int l15  = lane & 15;
    const int quad = lane >> 4;

    // A: m(batch) = l15, k = quad*8 + j   B: n(oc) = l15, k = quad*8 + j
    const _Float16* xrow = xs + l15 * XS2 + quad * 8;
    const _Float16* wrow = wks + (size_t)(w * 16 + l15) * KPAD + quad * 8;

    f32x4 res[NSEC];                // 36 VGPRs of final per-section maxes

    for (int s = 0; s < NSEC; ++s) {
        const _Float16* wsec = wrow + (size_t)s * (NOCP * KPAD);
        half8 bv[8];
        #pragma unroll
        for (int kk = 0; kk < 8; ++kk)
            bv[kk] = *(const half8*)(wsec + kk * 32);

        f32x4 acc[4] = {f32x4{}, f32x4{}, f32x4{}, f32x4{}};
        const _Float16* xsec = xrow + s * 160;
        #pragma unroll
        for (int kk = 0; kk < 8; ++kk) {
            #pragma unroll
            for (int h = 0; h < 4; ++h) {
                half8 av = *(const half8*)(xsec + h * 40 + kk * 32);
                acc[h] = __builtin_amdgcn_mfma_f32_16x16x32_f16(
                             av, bv[kk], acc[h], 0, 0, 0);
            }
        }
        // max over the 4 conv positions (pooling)
        f32x4 r;
        #pragma unroll
        for (int j = 0; j < 4; ++j)
            r[j] = fmaxf(fmaxf(acc[0][j], acc[1][j]),
                         fmaxf(acc[2][j], acc[3][j]));
        res[s] = r;
    }

    // reuse xs as fp32 transpose buffer t[16][450]
    __syncthreads();
    float* t = (float*)xs;
    const int oc = w * 16 + l15;    // D: col(oc)=l15, row(batch)=quad*4+r
    if (oc < NOC) {
        #pragma unroll
        for (int s = 0; s < NSEC; ++s)
            #pragma unroll
            for (int r = 0; r < 4; ++r)
                t[(quad * 4 + r) * 450 + oc * 9 + s] = res[s][r];
    }
    __syncthreads();

    // coalesced final write: pots then spikes
    const size_t ob = b0 * 450;
    for (int i = tid; i < TB * 450; i += 256) {
        float v = t[i];
        out[ob + i] = v;
        out[OUTHALF + ob + i] = (v > THRESH) ? 1.0f : 0.0f;
    }
}

// ---- fallback (only if ws too small): direct fp32, correct but slow ----
__global__ __launch_bounds__(256)
void naive_kernel(const float* __restrict__ x, const float* __restrict__ W,
                  float* __restrict__ out) {
    size_t idx = (size_t)blockIdx.x * 256 + threadIdx.x;
    if (idx >= OUTHALF) return;
    int s  = (int)(idx % NSEC);
    int oc = (int)((idx / NSEC) % NOC);
    int b  = (int)(idx / (NSEC * NOC));
    const float* xb = x + (size_t)b * XROW + s * 160;
    const float* wv = W + (size_t)(s * NOC + oc) * KREAL;
    float best = -1e30f;
    for (int h0 = 0; h0 < 4; ++h0) {
        float acc = 0.0f;
        for (int k = 0; k < KREAL; ++k)
            acc += xb[h0 * 40 + k] * wv[k];
        best = fmaxf(best, acc);
    }
    out[idx] = best;
    out[OUTHALF + idx] = (best > THRESH) ? 1.0f : 0.0f;
}

extern "C" void kernel_launch(void* const* d_in, const int* in_sizes, int n_in,
                              void* d_out, int out_size, void* d_ws, size_t ws_size,
                              hipStream_t stream) {
    const float* x = (const float*)d_in[0];   // [16384,1,41,40]
    const float* W = (const float*)d_in[1];   // [9,50,1,6,40]
    float* out = (float*)d_out;               // pots(7372800) ++ spks(7372800)

    const size_t w_bytes = (size_t)NSEC * NOCP * KPAD * sizeof(_Float16); // 294912

    if (ws_size < w_bytes) {
        naive_kernel<<<(OUTHALF + 255) / 256, 256, 0, stream>>>(x, W, out);
        return;
    }

    _Float16* wks = (_Float16*)d_ws;

    wconv_kernel<<<(NSEC * NOCP * KPAD) / 256, 256, 0, stream>>>(W, wks);
    fused_kernel<<<NBATCH / TB, 256, 0, stream>>>(x, wks, out);
}

// Round 3
// 216.053 us; speedup vs baseline: 1.1064x; 1.0954x over previous
//
#include <hip/hip_runtime.h>
#include <cstdint>
#include <cstddef>

// ---- problem constants ----
#define NBATCH   16384
#define NSEC     9
#define NOC      50        // conv output channels per section
#define NOCP     64        // padded to 4 MFMA n-tiles
#define KPAD     256       // padded K for 8 x 32 MFMA steps
#define KREAL    240
#define XROW     1640      // 41*40 floats per batch
#define XUNITS   208       // 16B-units per LDS row (205 real + 3 zero pad)
#define XSF      1664      // f16 elems per LDS row = XUNITS*8
#define TB       16        // batches per block
#define OUTHALF  7372800   // 16384*50*9
#define THRESH   6.2f

typedef _Float16 half8  __attribute__((ext_vector_type(8)));
typedef float    f32x4  __attribute__((ext_vector_type(4)));

// ---- k0: W fp32 [9][50][240] -> f16 [9][64][256], zero padded ----
__global__ __launch_bounds__(256)
void wconv_kernel(const float* __restrict__ W, _Float16* __restrict__ wks) {
    int idx = blockIdx.x * 256 + threadIdx.x;        // 0 .. 147455
    int k   = idx & 255;
    int ocp = (idx >> 8) & 63;
    int sec = idx >> 14;
    float v = 0.0f;
    if (ocp < NOC && k < KREAL)
        v = W[(size_t)(sec * NOC + ocp) * KREAL + k];
    wks[idx] = (_Float16)v;
}

// ---- fused: 16 batches x 9 sections per block; XOR-swizzled f16 LDS;
//      batched register staging for memory-level parallelism ----
__global__ __launch_bounds__(256, 3)
void fused_kernel(const float* __restrict__ x,
                  const _Float16* __restrict__ wks,
                  float* __restrict__ out) {
    __shared__ __align__(16) _Float16 xs[TB * XSF];   // 53248 B; 3 blocks/CU

    const int tid = threadIdx.x;
    const size_t b0 = (size_t)blockIdx.x * TB;

    // ---- staging: thread t owns row b=t>>4, units u = (t&15)+16j, j=0..12.
    // element k of row b lives at unit ((k>>3) ^ (b&7)), preserving 16B runs.
    {
        const int bb  = tid >> 4;
        const int u16 = tid & 15;
        const int sw  = bb & 7;
        const float* xrow = x + (b0 + bb) * XROW;
        _Float16* lrow = xs + bb * XSF;

        #pragma unroll
        for (int c = 0; c < 2; ++c) {
            const int jn = c ? 6 : 7;
            float4 va[7], vb[7];
            #pragma unroll
            for (int jj = 0; jj < 7; ++jj) {
                if (jj < jn) {
                    int u = u16 + 16 * (c * 7 + jj);
                    if (u < 205) {               // 205*8 == 1640 exactly
                        va[jj] = *(const float4*)(xrow + u * 8);
                        vb[jj] = *(const float4*)(xrow + u * 8 + 4);
                    } else {
                        va[jj] = float4{0, 0, 0, 0};
                        vb[jj] = float4{0, 0, 0, 0};
                    }
                }
            }
            #pragma unroll
            for (int jj = 0; jj < 7; ++jj) {
                if (jj < jn) {
                    int u = u16 + 16 * (c * 7 + jj);
                    half8 h;
                    h[0] = (_Float16)va[jj].x; h[1] = (_Float16)va[jj].y;
                    h[2] = (_Float16)va[jj].z; h[3] = (_Float16)va[jj].w;
                    h[4] = (_Float16)vb[jj].x; h[5] = (_Float16)vb[jj].y;
                    h[6] = (_Float16)vb[jj].z; h[7] = (_Float16)vb[jj].w;
                    *(half8*)(lrow + ((u ^ sw) << 3)) = h;
                }
            }
        }
    }
    __syncthreads();

    const int lane = tid & 63;
    const int w    = tid >> 6;      // wave = oc tile (16 oc each)
    const int l15  = lane & 15;
    const int quad = lane >> 4;
    const int sw   = l15 & 7;       // row-swizzle for A reads

    // A: m(batch)=l15, k=quad*8+j.  B: n(oc)=l15, k=quad*8+j.
    const _Float16* arow = xs + l15 * XSF;
    const _Float16* wrow = wks + (size_t)(w * 16 + l15) * KPAD + quad * 8;

    f32x4 res[NSEC];

    for (int s = 0; s < NSEC; ++s) {
        const _Float16* wsec = wrow + (size_t)s * (NOCP * KPAD);
        half8 bv[8];
        #pragma unroll
        for (int kk = 0; kk < 8; ++kk)
            bv[kk] = *(const half8*)(wsec + kk * 32);

        f32x4 acc[4] = {f32x4{}, f32x4{}, f32x4{}, f32x4{}};
        const int su = s * 20 + quad;   // base 16B-unit: s*160 elems /8 + quad
        #pragma unroll
        for (int kk = 0; kk < 8; ++kk) {
            #pragma unroll
            for (int h = 0; h < 4; ++h) {
                int unit = su + h * 5 + kk * 4;      // +h*40/8 +kk*32/8
                half8 av = *(const half8*)(arow + ((unit ^ sw) << 3));
                acc[h] = __builtin_amdgcn_mfma_f32_16x16x32_f16(
                             av, bv[kk], acc[h], 0, 0, 0);
            }
        }
        f32x4 r;
        #pragma unroll
        for (int j = 0; j < 4; ++j)
            r[j] = fmaxf(fmaxf(acc[0][j], acc[1][j]),
                         fmaxf(acc[2][j], acc[3][j]));
        res[s] = r;
    }

    // reuse xs as fp32 transpose buffer t[16][450]
    __syncthreads();
    float* t = (float*)xs;
    const int oc = w * 16 + l15;    // D: col(oc)=l15, row(batch)=quad*4+r
    if (oc < NOC) {
        #pragma unroll
        for (int s = 0; s < NSEC; ++s)
            #pragma unroll
            for (int r = 0; r < 4; ++r)
                t[(quad * 4 + r) * 450 + oc * 9 + s] = res[s][r];
    }
    __syncthreads();

    // coalesced final write: pots then spikes
    const size_t ob = b0 * 450;
    for (int i = tid; i < TB * 450; i += 256) {
        float v = t[i];
        out[ob + i] = v;
        out[OUTHALF + ob + i] = (v > THRESH) ? 1.0f : 0.0f;
    }
}

// ---- fallback (only if ws too small): direct fp32, correct but slow ----
__global__ __launch_bounds__(256)
void naive_kernel(const float* __restrict__ x, const float* __restrict__ W,
                  float* __restrict__ out) {
    size_t idx = (size_t)blockIdx.x * 256 + threadIdx.x;
    if (idx >= OUTHALF) return;
    int s  = (int)(idx % NSEC);
    int oc = (int)((idx / NSEC) % NOC);
    int b  = (int)(idx / (NSEC * NOC));
    const float* xb = x + (size_t)b * XROW + s * 160;
    const float* wv = W + (size_t)(s * NOC + oc) * KREAL;
    float best = -1e30f;
    for (int h0 = 0; h0 < 4; ++h0) {
        float acc = 0.0f;
        for (int k = 0; k < KREAL; ++k)
            acc += xb[h0 * 40 + k] * wv[k];
        best = fmaxf(best, acc);
    }
    out[idx] = best;
    out[OUTHALF + idx] = (best > THRESH) ? 1.0f : 0.0f;
}

extern "C" void kernel_launch(void* const* d_in, const int* in_sizes, int n_in,
                              void* d_out, int out_size, void* d_ws, size_t ws_size,
                              hipStream_t stream) {
    const float* x = (const float*)d_in[0];   // [16384,1,41,40]
    const float* W = (const float*)d_in[1];   // [9,50,1,6,40]
    float* out = (float*)d_out;               // pots(7372800) ++ spks(7372800)

    const size_t w_bytes = (size_t)NSEC * NOCP * KPAD * sizeof(_Float16); // 294912

    if (ws_size < w_bytes) {
        naive_kernel<<<(OUTHALF + 255) / 256, 256, 0, stream>>>(x, W, out);
        return;
    }

    _Float16* wks = (_Float16*)d_ws;

    wconv_kernel<<<(NSEC * NOCP * KPAD) / 256, 256, 0, stream>>>(W, wks);
    fused_kernel<<<NBATCH / TB, 256, 0, stream>>>(x, wks, out);
}